// Round 2
// baseline (141.780 us; speedup 1.0000x reference)
//
#include <hip/hip_runtime.h>
#include <cstdint>
#include <cstddef>

#define NPTS 8192
#define NWORDS 128          // NPTS/64
#define NUM_CLASSES 5
#define XCOLS 10            // 3 coords + batch + feat + 5 seg
#define MIN_PTS 5
#define NGROUPS 10
#define BIGC 0x3fffffff

#define NLCAP 1536          // max nodes per group (expect ~820)
#define EACAP 8192          // per-group eps-pairs u<v (expect ~5.4k)
#define ELCAP 8192          // core-core edges
#define EBCAP 2048          // core-noncore edges
#define CPAD 64             // per-group counters padded 256 B apart
#define NSLICE 24           // row slices per group (rows r == s mod 24)
#define NRPS (NLCAP / NSLICE)   // 64 rows per slice -> exactly one per lane
#define NTHREADS 512
#define NWAVES 8
#define ROUNDS 16

// ---------------- init: per-point group argmax + zero counters ---------------
__global__ void k_init(const float* __restrict__ x, int* __restrict__ grp,
                       unsigned int* __restrict__ gcnt, unsigned int* __restrict__ gdone) {
    int i = blockIdx.x * blockDim.x + threadIdx.x;
    if (i < NGROUPS * CPAD) { gcnt[i] = 0u; gdone[i] = 0u; }
    if (i >= NPTS) return;
    const float* r = x + (size_t)i * XCOLS;
    // rows are 40 B -> always 8-byte aligned: load as float2 pairs
    const float2* r2 = (const float2*)r;
    float2 c23 = r2[1];                 // z, batch
    float2 c45 = r2[2];                 // feat, s0
    float2 c67 = r2[3];                 // s1, s2
    float2 c89 = r2[4];                 // s3, s4
    float best = c45.y; int bc = 0;
    if (c67.x > best) { best = c67.x; bc = 1; }
    if (c67.y > best) { best = c67.y; bc = 2; }
    if (c89.x > best) { best = c89.x; bc = 3; }
    if (c89.y > best) { best = c89.y; bc = 4; }
    grp[i] = (int)c23.y * NUM_CLASSES + bc;
}

// ---------------- main: prep + pairs slice + (last block) graph --------------
// grid = 10*24 blocks, 512 threads (8 waves). Each block:
//   A) rebuilds its group's ordered node list from grp (ballot+prefix) and
//      fills pts[] in LDS (w = 0.5*|p|^2 - EPS2/4; test: dot > wu+wv)
//   B) computes its row slice (rows r == s mod 24, one row per lane; the 8
//      waves partition the column chunks) -> edges to global + full-row degree
//   C) fences, bumps gdone[g]; the LAST slice block of the group continues
//      into the graph phase (classify -> SV -> rank -> border -> output).
__global__ void __launch_bounds__(NTHREADS) k_main(
        const float* __restrict__ x, const int* __restrict__ grp,
        unsigned int* __restrict__ eAll_g, unsigned int* __restrict__ gcnt,
        int* __restrict__ deg_g, unsigned int* __restrict__ gdone,
        float* __restrict__ out) {
    // ---- phase A/B state
    __shared__ float4 pts[NLCAP];                    // 24 KB
    __shared__ unsigned long long masks[NWORDS];     // 1 KB
    __shared__ int pref[NWORDS];                     // 0.5 KB
    __shared__ int nlist[NLCAP];                     // 6 KB
    __shared__ int srowdeg[NRPS];                    // 256 B
    __shared__ int nnS, lastS;
    // ---- phase C state
    __shared__ unsigned int eA[EACAP];               // 32 KB
    __shared__ unsigned int eL[ELCAP];               // 32 KB
    __shared__ unsigned int eB[EBCAP];               // 8 KB
    __shared__ int sdeg[NLCAP];                      // 6 KB
    __shared__ int spar[NLCAP];                      // 6 KB
    __shared__ int scid[NLCAP];                      // 6 KB
    __shared__ int sbmin[NLCAP];                     // 6 KB
    __shared__ unsigned long long corebm[NLCAP/64];  // 192 B
    __shared__ unsigned long long repbm[NLCAP/64];   // 192 B
    __shared__ int nL, nB;
    __shared__ int sflagA[ROUNDS];

    const int g = blockIdx.x / NSLICE;
    const int s = blockIdx.x % NSLICE;
    const int tid = threadIdx.x, lane = tid & 63, wv = tid >> 6;

    // ---- A: membership -> ordered node list + pts in LDS
    for (int k = tid; k < NLCAP; k += NTHREADS)
        pts[k] = make_float4(0.f, 0.f, 0.f, 1.0e38f);     // sentinel w
    if (tid < NRPS) srowdeg[tid] = 0;
    for (int w = wv; w < NWORDS; w += NWAVES) {
        unsigned long long bm = __ballot(grp[w * 64 + lane] == g);
        if (lane == 0) masks[w] = bm;
    }
    __syncthreads();
    if (wv == 0) {                         // 2-chunk scan of 128 popcounts
        int v0 = __popcll(masks[lane]);
        int incl = v0;
        #pragma unroll
        for (int st = 1; st < 64; st <<= 1) {
            int o = __shfl_up(incl, st);
            if (lane >= st) incl += o;
        }
        pref[lane] = incl - v0;
        int tot0 = __shfl(incl, 63);
        int v1 = __popcll(masks[64 + lane]);
        int incl1 = v1;
        #pragma unroll
        for (int st = 1; st < 64; st <<= 1) {
            int o = __shfl_up(incl1, st);
            if (lane >= st) incl1 += o;
        }
        pref[64 + lane] = tot0 + incl1 - v1;
        if (lane == 63) nnS = tot0 + incl1;
    }
    __syncthreads();
    for (int w = wv; w < NWORDS; w += NWAVES) {
        unsigned long long bm = masks[w];
        if ((bm >> lane) & 1ull) {
            int p = pref[w] + __popcll(bm & ((1ull << lane) - 1ull));
            if (p < NLCAP) {
                int i = w * 64 + lane;
                const float2* r2 = (const float2*)(x + (size_t)i * XCOLS);
                float2 c01 = r2[0]; float2 c23 = r2[1];
                float px = c01.x, py = c01.y, pz = c23.x;
                // w = 0.5|p|^2 - EPS2/4 ; then d2<EPS2 <=> dot(u,v) > wu+wv
                pts[p] = make_float4(px, py, pz,
                                     0.5f * (px*px + py*py + pz*pz) - 56.25f);
                nlist[p] = i;
            }
        }
    }
    __syncthreads();
    const int NN = (nnS > NLCAP) ? NLCAP : nnS;

    // ---- B: pair slice. lane owns row rrow; waves partition column chunks.
    const int rrow = s + NSLICE * lane;               // 0..1535, exactly NLCAP
    const float4 qu = pts[rrow];
    int rdeg = 0;
    const int NC = (NN + 31) >> 5;
    unsigned int* eg = eAll_g + (size_t)g * EACAP;
    for (int c = wv; c < NC; c += NWAVES) {
        int base = c << 5;
        unsigned int bits = 0u;
        #pragma unroll
        for (int t = 0; t < 32; t++) {
            float4 qv = pts[base + t];                // wave-uniform broadcast
            float dt = qu.x*qv.x + qu.y*qv.y + qu.z*qv.z;
            bits |= (dt > qu.w + qv.w) ? (1u << t) : 0u;
        }
        rdeg += __popc(bits);                          // full-row degree (incl self)
        int d = rrow - base;                           // keep only v > u for edges
        if (d >= 31) bits = 0u;
        else if (d >= 0) bits &= ~((2u << d) - 1u);
        int cnt = __popc(bits);
        int incl = cnt;
        #pragma unroll
        for (int st = 1; st < 64; st <<= 1) {
            int o = __shfl_up(incl, st);
            if (lane >= st) incl += o;
        }
        int tot = __shfl(incl, 63);
        if (tot > 0) {
            unsigned int rbase = 0;
            if (lane == 63) rbase = atomicAdd(&gcnt[g * CPAD], (unsigned int)tot);
            rbase = __shfl(rbase, 63);
            unsigned int p = rbase + (unsigned int)(incl - cnt);
            unsigned int b = bits;
            unsigned int uhi = (unsigned int)rrow << 11;
            while (b) {
                int t = __ffs(b) - 1; b &= b - 1;
                if (p < EACAP) eg[p] = uhi | (unsigned int)(base + t);
                p++;
            }
        }
    }
    if (rdeg > 0) atomicAdd(&srowdeg[lane], rdeg);    // sum across the 8 waves
    __syncthreads();
    if (tid < NRPS)
        deg_g[g * NLCAP + s + NSLICE * tid] = srowdeg[tid];

    // ---- C0: publish stores, elect the last slice block of this group
    __threadfence();                                   // release my global stores
    __syncthreads();
    if (tid == 0) {
        unsigned int old = __hip_atomic_fetch_add(&gdone[g * CPAD], 1u,
                              __ATOMIC_ACQ_REL, __HIP_MEMORY_SCOPE_AGENT);
        lastS = (old == NSLICE - 1) ? 1 : 0;
    }
    __syncthreads();
    if (!lastS) return;                                // uniform per block
    __threadfence();                                   // acquire side

    // ---- C: graph phase (one surviving block per group)
    const unsigned int Eu = gcnt[g * CPAD];
    const int NA = (Eu > (unsigned)EACAP) ? EACAP : (int)Eu;
    if (tid == 0) { nL = 0; nB = 0; }
    if (tid < ROUNDS) sflagA[tid] = 0;
    for (int k = tid; k < NLCAP; k += NTHREADS) {
        sdeg[k] = deg_g[g * NLCAP + k];
        spar[k] = k;
        sbmin[k] = BIGC;
    }
    for (int e = tid; e < NA; e += NTHREADS) eA[e] = eg[e];
    __syncthreads();
    // core bitmap (degrees are already full-row counts incl self)
    for (int w = wv; w < NLCAP / 64; w += NWAVES) {
        int l = w * 64 + lane;
        bool isc = (l < NN) && (sdeg[l] >= MIN_PTS);
        unsigned long long bm = __ballot(isc);
        if (lane == 0) corebm[w] = bm;
    }
    __syncthreads();
    auto corebit = [&](int l) -> bool { return (corebm[l >> 6] >> (l & 63)) & 1ull; };

    // classify eA -> eL / eB (wave-aggregated)
    for (int e0 = 0; e0 < NA; e0 += NTHREADS) {
        int e = e0 + tid;
        unsigned int pk = (e < NA) ? eA[e] : 0u;
        bool val = (e < NA);
        int u = (int)(pk >> 11), v = (int)(pk & 2047u);
        bool cu = val && corebit(u), cv = val && corebit(v);
        bool isL = cu && cv, isB = val && (cu != cv);
        unsigned long long mL = __ballot(isL);
        if (mL) {
            int b0 = 0;
            if (lane == 0) b0 = atomicAdd(&nL, __popcll(mL));
            b0 = __shfl(b0, 0);
            if (isL) {
                int idx = b0 + __popcll(mL & ((1ull << lane) - 1ull));
                if (idx < ELCAP) eL[idx] = pk;
            }
        }
        unsigned long long mB = __ballot(isB);
        if (mB) {
            int b0 = 0;
            if (lane == 0) b0 = atomicAdd(&nB, __popcll(mB));
            b0 = __shfl(b0, 0);
            if (isB) {
                int idx = b0 + __popcll(mB & ((1ull << lane) - 1ull));
                if (idx < EBCAP) eB[idx] = pk;
            }
        }
    }
    __syncthreads();
    const int NL = (nL > ELCAP) ? ELCAP : nL;
    const int NB = (nB > EBCAP) ? EBCAP : nB;

    // SV rounds: hook-to-min + double pointer jump, 2 barriers/round
    for (int r = 0; r < ROUNDS; r++) {
        for (int k = tid; k < NL; k += NTHREADS) {
            unsigned int pk = eL[k];
            int u = (int)(pk >> 11), v = (int)(pk & 2047u);
            int a = spar[u], b2 = spar[v];
            if (a < b2)      { int old = atomicMin(&spar[v], a);  if (old > a)  sflagA[r] = 1; }
            else if (b2 < a) { int old = atomicMin(&spar[u], b2); if (old > b2) sflagA[r] = 1; }
        }
        __syncthreads();
        for (int k = tid; k < NN; k += NTHREADS) {
            int sp = spar[k]; int s2 = spar[sp];
            if (s2 < sp) { int s3 = spar[s2]; spar[k] = (s3 < s2) ? s3 : s2; sflagA[r] = 1; }
        }
        __syncthreads();
        if (!sflagA[r]) break;
    }

    // reps + rank (wave 0 serial over 24 words)
    for (int w = wv; w < NLCAP / 64; w += NWAVES) {
        int l = w * 64 + lane;
        bool isr = (l < NN) && corebit(l) && (spar[l] == l);
        unsigned long long bm = __ballot(isr);
        if (lane == 0) repbm[w] = bm;
    }
    __syncthreads();
    if (wv == 0) {
        int running = 0;
        for (int w = 0; w < NLCAP / 64; w++) {
            unsigned long long bm = repbm[w];
            if ((bm >> lane) & 1ull)
                scid[w * 64 + lane] = running + __popcll(bm & ((1ull << lane) - 1ull));
            running += __popcll(bm);
        }
    }
    __syncthreads();
    // core cluster id -> overwrite spar
    int cc[3];
    #pragma unroll
    for (int t = 0; t < 3; t++) {
        int k = tid + t * NTHREADS;
        cc[t] = (k < NN && corebit(k)) ? scid[spar[k]] : BIGC;
    }
    __syncthreads();
    #pragma unroll
    for (int t = 0; t < 3; t++) {
        int k = tid + t * NTHREADS;
        if (k < NN) spar[k] = cc[t];
    }
    __syncthreads();
    // border: min adjacent core cid for the non-core endpoint
    for (int k = tid; k < NB; k += NTHREADS) {
        unsigned int pk = eB[k];
        int u = (int)(pk >> 11), v = (int)(pk & 2047u);
        int cu = spar[u], cv = spar[v];
        if (cu == BIGC) atomicMin(&sbmin[u], cv);
        else            atomicMin(&sbmin[v], cu);
    }
    __syncthreads();
    // final labels + clustered output
    for (int k = tid; k < NN; k += NTHREADS) {
        int i = nlist[k];
        int c = spar[k];
        int lbl = (c != BIGC) ? c : ((sbmin[k] < BIGC) ? sbmin[k] : -1);
        out[i] = (float)lbl;
        const float* r = x + (size_t)i * XCOLS;
        float* o = out + NPTS + (size_t)i * 5;
        bool keep = lbl >= 0;
        #pragma unroll
        for (int c5 = 0; c5 < 5; c5++) o[c5] = keep ? r[c5] : 0.0f;
    }
}

extern "C" void kernel_launch(void* const* d_in, const int* in_sizes, int n_in,
                              void* d_out, int out_size, void* d_ws, size_t ws_size,
                              hipStream_t stream) {
    const float* x = (const float*)d_in[0];
    float* out = (float*)d_out;
    char* ws = (char*)d_ws;

    // workspace layout (~430 KB)
    int* grp            = (int*)(ws);                     // 32768 B
    unsigned int* gcnt  = (unsigned int*)(ws + 32768);    // 10*64*4 = 2560
    unsigned int* gdone = (unsigned int*)(ws + 35328);    // 2560
    int* deg_g          = (int*)(ws + 37888);             // 10*1536*4 = 61440
    unsigned int* eAll_g= (unsigned int*)(ws + 99328);    // 10*8192*4 = 327680

    k_init<<<NPTS / 256, 256, 0, stream>>>(x, grp, gcnt, gdone);
    k_main<<<NGROUPS * NSLICE, NTHREADS, 0, stream>>>(x, grp, eAll_g, gcnt,
                                                      deg_g, gdone, out);
}

// Round 3
// 92.697 us; speedup vs baseline: 1.5295x; 1.5295x over previous
//
#include <hip/hip_runtime.h>
#include <cstdint>
#include <cstddef>

#define NPTS 8192
#define NWORDS 128          // NPTS/64
#define NUM_CLASSES 5
#define XCOLS 10            // 3 coords + batch + feat + 5 seg
#define MIN_PTS 5
#define NGROUPS 10
#define BIGC 0x3fffffff

#define NLCAP 1536          // max nodes per group (expect ~820)
#define EACAP 8192          // per-group eps-pairs u<v (expect ~5.4k)
#define ELCAP 8192          // core-core edges
#define EBCAP 2048          // core-noncore edges
#define CPAD 64             // per-group counters padded 256 B apart
#define NSLICE 24           // row slices per group (rows r == s mod 24)
#define PTHREADS 512        // k_pairs block (8 waves)
#define PWAVES 8
#define GTHREADS 1024       // k_graph block (16 waves)
#define ROUNDS 16

// ---------------- init: per-point group argmax + zero counters ---------------
__global__ void k_init(const float* __restrict__ x, int* __restrict__ grp,
                       unsigned int* __restrict__ gcnt) {
    int i = blockIdx.x * blockDim.x + threadIdx.x;
    if (i < NGROUPS * CPAD) gcnt[i] = 0u;
    if (i >= NPTS) return;
    const float2* r2 = (const float2*)(x + (size_t)i * XCOLS);   // rows 40 B, 8-aligned
    float2 c23 = r2[1];                 // z, batch
    float2 c45 = r2[2];                 // feat, s0
    float2 c67 = r2[3];                 // s1, s2
    float2 c89 = r2[4];                 // s3, s4
    float best = c45.y; int bc = 0;
    if (c67.x > best) { best = c67.x; bc = 1; }
    if (c67.y > best) { best = c67.y; bc = 2; }
    if (c89.x > best) { best = c89.x; bc = 3; }
    if (c89.y > best) { best = c89.y; bc = 4; }
    grp[i] = (int)c23.y * NUM_CLASSES + bc;
}

// ---------------- pairs: rebuild node list + row-slice adjacency -------------
// grid = 10*24, 512 threads. Each block rebuilds its group's ordered node list
// from grp (ballot+prefix over 128 words), fills pts[] in LDS
// (w = 0.5|p|^2 - EPS2/4; test: dot > wu+wv), then computes rows r==s (mod 24)
// (one row per lane, 8 waves partition column chunks). Emits packed edges
// (u<v) to global and FULL-row degrees (self included) so k_graph needs no
// degree pass. Slice 0 also persists nlist/nn for k_graph.
__global__ void __launch_bounds__(PTHREADS) k_pairs(
        const float* __restrict__ x, const int* __restrict__ grp,
        unsigned int* __restrict__ eAll_g, unsigned int* __restrict__ gcnt,
        int* __restrict__ deg_g, int* __restrict__ nlist_g, int* __restrict__ nn_g) {
    __shared__ float4 pts[NLCAP];                    // 24 KB
    __shared__ unsigned long long masks[NWORDS];     // 1 KB
    __shared__ int pref[NWORDS];                     // 0.5 KB
    __shared__ int srowdeg[64];                      // 256 B
    __shared__ int nnS;

    const int g = blockIdx.x / NSLICE;
    const int s = blockIdx.x % NSLICE;
    const int tid = threadIdx.x, lane = tid & 63, wv = tid >> 6;

    for (int k = tid; k < NLCAP; k += PTHREADS)
        pts[k] = make_float4(0.f, 0.f, 0.f, 1.0e38f);     // sentinel w
    if (tid < 64) srowdeg[tid] = 0;
    for (int w = wv; w < NWORDS; w += PWAVES) {
        unsigned long long bm = __ballot(grp[w * 64 + lane] == g);
        if (lane == 0) masks[w] = bm;
    }
    __syncthreads();
    if (wv == 0) {                         // 2-chunk scan of 128 popcounts
        int v0 = __popcll(masks[lane]);
        int incl = v0;
        #pragma unroll
        for (int st = 1; st < 64; st <<= 1) {
            int o = __shfl_up(incl, st);
            if (lane >= st) incl += o;
        }
        pref[lane] = incl - v0;
        int tot0 = __shfl(incl, 63);
        int v1 = __popcll(masks[64 + lane]);
        int incl1 = v1;
        #pragma unroll
        for (int st = 1; st < 64; st <<= 1) {
            int o = __shfl_up(incl1, st);
            if (lane >= st) incl1 += o;
        }
        pref[64 + lane] = tot0 + incl1 - v1;
        if (lane == 63) nnS = tot0 + incl1;
    }
    __syncthreads();
    for (int w = wv; w < NWORDS; w += PWAVES) {
        unsigned long long bm = masks[w];
        if ((bm >> lane) & 1ull) {
            int p = pref[w] + __popcll(bm & ((1ull << lane) - 1ull));
            if (p < NLCAP) {
                int i = w * 64 + lane;
                const float2* r2 = (const float2*)(x + (size_t)i * XCOLS);
                float2 c01 = r2[0]; float2 c23 = r2[1];
                float px = c01.x, py = c01.y, pz = c23.x;
                pts[p] = make_float4(px, py, pz,
                                     0.5f * (px*px + py*py + pz*pz) - 56.25f);
                if (s == 0) nlist_g[g * NLCAP + p] = i;
            }
        }
    }
    if (s == 0 && tid == 0) nn_g[g] = (nnS > NLCAP) ? NLCAP : nnS;
    __syncthreads();
    const int NN = (nnS > NLCAP) ? NLCAP : nnS;

    // row slice: lane owns row rrow; waves partition the column chunks
    const int rrow = s + NSLICE * lane;               // covers 0..1535 exactly
    const float4 qu = pts[rrow];
    int rdeg = 0;
    const int NC = (NN + 31) >> 5;
    unsigned int* eg = eAll_g + (size_t)g * EACAP;
    for (int c = wv; c < NC; c += PWAVES) {
        int base = c << 5;
        unsigned int bits = 0u;
        #pragma unroll
        for (int t = 0; t < 32; t++) {
            float4 qv = pts[base + t];                // wave-uniform broadcast
            float dt = qu.x*qv.x + qu.y*qv.y + qu.z*qv.z;
            bits |= (dt > qu.w + qv.w) ? (1u << t) : 0u;
        }
        rdeg += __popc(bits);                          // full-row degree (incl self)
        int d = rrow - base;                           // keep only v > u for edges
        if (d >= 31) bits = 0u;
        else if (d >= 0) bits &= ~((2u << d) - 1u);
        int cnt = __popc(bits);
        int incl = cnt;
        #pragma unroll
        for (int st = 1; st < 64; st <<= 1) {
            int o = __shfl_up(incl, st);
            if (lane >= st) incl += o;
        }
        int tot = __shfl(incl, 63);
        if (tot > 0) {
            unsigned int rbase = 0;
            if (lane == 63) rbase = atomicAdd(&gcnt[g * CPAD], (unsigned int)tot);
            rbase = __shfl(rbase, 63);
            unsigned int p = rbase + (unsigned int)(incl - cnt);
            unsigned int b = bits;
            unsigned int uhi = (unsigned int)rrow << 11;
            while (b) {
                int t = __ffs(b) - 1; b &= b - 1;
                if (p < EACAP) eg[p] = uhi | (unsigned int)(base + t);
                p++;
            }
        }
    }
    if (rdeg > 0) atomicAdd(&srowdeg[lane], rdeg);    // sum across the 8 waves
    __syncthreads();
    if (tid < 64)
        deg_g[g * NLCAP + s + NSLICE * tid] = srowdeg[tid];
}

// ---------------- graph: core -> classify -> SV(find+compress) -> output ----
__global__ void __launch_bounds__(GTHREADS) k_graph(
        const unsigned int* __restrict__ eAll_g, const unsigned int* __restrict__ gcnt,
        const int* __restrict__ deg_g, const int* __restrict__ nlist_g,
        const int* __restrict__ nn_g, const float* __restrict__ x,
        float* __restrict__ out) {
    __shared__ unsigned int eL[ELCAP];               // 32 KB
    __shared__ unsigned int eB[EBCAP];               // 8 KB
    __shared__ int spar[NLCAP];                      // 6 KB
    __shared__ int scid[NLCAP];                      // 6 KB
    __shared__ int sbmin[NLCAP];                     // 6 KB
    __shared__ int nlist[NLCAP];                     // 6 KB
    __shared__ unsigned long long corebm[NLCAP/64];  // 192 B
    __shared__ unsigned long long repbm[NLCAP/64];   // 192 B
    __shared__ int pref24[NLCAP/64];
    __shared__ int nL, nB;
    __shared__ int sflagA[ROUNDS];

    const int g = blockIdx.x;
    const int tid = threadIdx.x, lane = tid & 63, wv = tid >> 6;
    const int NN = nn_g[g];
    const unsigned int Eu = gcnt[g * CPAD];
    const int NA = (Eu > (unsigned)EACAP) ? EACAP : (int)Eu;
    const unsigned int* eg = eAll_g + (size_t)g * EACAP;

    if (tid == 0) { nL = 0; nB = 0; }
    if (tid < ROUNDS) sflagA[tid] = 0;
    for (int k = tid; k < NLCAP; k += GTHREADS) {
        spar[k] = k;
        sbmin[k] = BIGC;
        nlist[k] = nlist_g[g * NLCAP + k];
    }
    // core bitmap straight from global degrees (full-row counts incl self)
    for (int w = wv; w < NLCAP / 64; w += 16) {
        int l = w * 64 + lane;
        bool isc = (l < NN) && (deg_g[g * NLCAP + l] >= MIN_PTS);
        unsigned long long bm = __ballot(isc);
        if (lane == 0) corebm[w] = bm;
    }
    __syncthreads();
    auto corebit = [&](int l) -> bool { return (corebm[l >> 6] >> (l & 63)) & 1ull; };

    // classify straight from global -> eL / eB (wave-aggregated compaction)
    for (int e0 = 0; e0 < NA; e0 += GTHREADS) {
        int e = e0 + tid;
        unsigned int pk = (e < NA) ? eg[e] : 0u;
        bool val = (e < NA);
        int u = (int)(pk >> 11), v = (int)(pk & 2047u);
        bool cu = val && corebit(u), cv = val && corebit(v);
        bool isL = cu && cv, isB = val && (cu != cv);
        unsigned long long mL = __ballot(isL);
        if (mL) {
            int b0 = 0;
            if (lane == 0) b0 = atomicAdd(&nL, __popcll(mL));
            b0 = __shfl(b0, 0);
            if (isL) {
                int idx = b0 + __popcll(mL & ((1ull << lane) - 1ull));
                if (idx < ELCAP) eL[idx] = pk;
            }
        }
        unsigned long long mB = __ballot(isB);
        if (mB) {
            int b0 = 0;
            if (lane == 0) b0 = atomicAdd(&nB, __popcll(mB));
            b0 = __shfl(b0, 0);
            if (isB) {
                int idx = b0 + __popcll(mB & ((1ull << lane) - 1ull));
                if (idx < EBCAP) eB[idx] = pk;
            }
        }
    }
    __syncthreads();
    const int NL = (nL > ELCAP) ? ELCAP : nL;
    const int NB = (nB > EBCAP) ? EBCAP : nB;

    // SV: find-root hook + full path compression (values only decrease)
    for (int r = 0; r < ROUNDS; r++) {
        for (int k = tid; k < NL; k += GTHREADS) {
            unsigned int pk = eL[k];
            int u = (int)(pk >> 11), v = (int)(pk & 2047u);
            int ru = spar[u];
            while (true) { int p = spar[ru]; if (p == ru) break; ru = p; }
            int rv = spar[v];
            while (true) { int p = spar[rv]; if (p == rv) break; rv = p; }
            if (ru < rv)      { if (atomicMin(&spar[rv], ru) > ru) sflagA[r] = 1; }
            else if (rv < ru) { if (atomicMin(&spar[ru], rv) > rv) sflagA[r] = 1; }
        }
        __syncthreads();
        for (int k = tid; k < NN; k += GTHREADS) {
            int p = spar[k];
            while (true) { int q = spar[p]; if (q == p) break; p = q; }
            spar[k] = p;
        }
        __syncthreads();
        if (!sflagA[r]) break;
    }

    // reps bitmap + parallel 24-word rank
    for (int w = wv; w < NLCAP / 64; w += 16) {
        int l = w * 64 + lane;
        bool isr = (l < NN) && corebit(l) && (spar[l] == l);
        unsigned long long bm = __ballot(isr);
        if (lane == 0) repbm[w] = bm;
    }
    __syncthreads();
    if (wv == 0 && lane < NLCAP / 64) {
        int c = __popcll(repbm[lane]);
        int incl = c;
        #pragma unroll
        for (int st = 1; st < 32; st <<= 1) {
            int o = __shfl_up(incl, st);
            if (lane >= st) incl += o;
        }
        pref24[lane] = incl - c;
    }
    __syncthreads();
    for (int w = wv; w < NLCAP / 64; w += 16) {
        int l = w * 64 + lane;
        unsigned long long bm = repbm[w];
        if ((bm >> lane) & 1ull)
            scid[l] = pref24[w] + __popcll(bm & ((1ull << lane) - 1ull));
    }
    __syncthreads();
    // core cluster id -> overwrite spar (read-all then write-all)
    int cc[2];
    #pragma unroll
    for (int t = 0; t < 2; t++) {
        int k = tid + t * GTHREADS;
        cc[t] = (k < NN && corebit(k)) ? scid[spar[k]] : BIGC;
    }
    __syncthreads();
    #pragma unroll
    for (int t = 0; t < 2; t++) {
        int k = tid + t * GTHREADS;
        if (k < NLCAP) spar[k] = (k < NN) ? cc[t] : BIGC;
    }
    __syncthreads();
    // border: min adjacent core cid for the non-core endpoint
    for (int k = tid; k < NB; k += GTHREADS) {
        unsigned int pk = eB[k];
        int u = (int)(pk >> 11), v = (int)(pk & 2047u);
        int cu = spar[u], cv = spar[v];
        if (cu == BIGC) atomicMin(&sbmin[u], cv);
        else            atomicMin(&sbmin[v], cu);
    }
    __syncthreads();
    // final labels + clustered output
    for (int k = tid; k < NN; k += GTHREADS) {
        int i = nlist[k];
        int c = spar[k];
        int lbl = (c != BIGC) ? c : ((sbmin[k] < BIGC) ? sbmin[k] : -1);
        out[i] = (float)lbl;
        const float* r = x + (size_t)i * XCOLS;
        float* o = out + NPTS + (size_t)i * 5;
        bool keep = lbl >= 0;
        #pragma unroll
        for (int c5 = 0; c5 < 5; c5++) o[c5] = keep ? r[c5] : 0.0f;
    }
}

extern "C" void kernel_launch(void* const* d_in, const int* in_sizes, int n_in,
                              void* d_out, int out_size, void* d_ws, size_t ws_size,
                              hipStream_t stream) {
    const float* x = (const float*)d_in[0];
    float* out = (float*)d_out;
    char* ws = (char*)d_ws;

    // workspace layout (~490 KB)
    int* grp            = (int*)(ws);                     // 32768 B
    unsigned int* gcnt  = (unsigned int*)(ws + 32768);    // 10*64*4 = 2560
    int* nn_g           = (int*)(ws + 35328);             // 64
    int* nlist_g        = (int*)(ws + 35392);             // 10*1536*4 = 61440
    int* deg_g          = (int*)(ws + 96832);             // 61440
    unsigned int* eAll_g= (unsigned int*)(ws + 158272);   // 10*8192*4 = 327680

    k_init<<<NPTS / 256, 256, 0, stream>>>(x, grp, gcnt);
    k_pairs<<<NGROUPS * NSLICE, PTHREADS, 0, stream>>>(x, grp, eAll_g, gcnt,
                                                       deg_g, nlist_g, nn_g);
    k_graph<<<NGROUPS, GTHREADS, 0, stream>>>(eAll_g, gcnt, deg_g, nlist_g,
                                              nn_g, x, out);
}